// Round 12
// baseline (241.148 us; speedup 1.0000x reference)
//
#include <hip/hip_runtime.h>
#include <hip/hip_bf16.h>

typedef unsigned short ushort_t;
typedef __bf16 bf16_t;
typedef bf16_t bf16x8 __attribute__((ext_vector_type(8)));
typedef unsigned short u16x8v __attribute__((ext_vector_type(8)));
typedef float f32x4 __attribute__((ext_vector_type(4)));
typedef unsigned uint32x2 __attribute__((ext_vector_type(2)));
typedef unsigned uint32x4 __attribute__((ext_vector_type(4)));

#define D 128
#define NB 8
#define DFFN 512
#define LN_EPS 1e-5f

// Barrier ordering LDS only: weight loads in flight are NOT drained.
#define BARRIER_LGKM() asm volatile("s_waitcnt lgkmcnt(0)\n\ts_barrier" ::: "memory")
// Barrier that also waits for global_load_lds completion.
#define BARRIER_VM()   asm volatile("s_waitcnt vmcnt(0) lgkmcnt(0)\n\ts_barrier" ::: "memory")
// Opaque register pin: redefines the value in-place so the compiler cannot
// rematerialize it from LDS (forces true register residency).
#define PIN(v) asm volatile("" : "+v"(v))

__device__ __forceinline__ ushort_t bf16_rne(float f) {
  union { float f; unsigned u; } c; c.f = f;
  unsigned u = c.u;
  unsigned r = (u + 0x7FFFu + ((u >> 16) & 1u)) >> 16;
  return (ushort_t)r;
}

__device__ __forceinline__ unsigned cvt_pk_bf16(float lo, float hi) {
  unsigned r;
  asm("v_cvt_pk_bf16_f32 %0, %1, %2" : "=v"(r) : "v"(lo), "v"(hi));
  return r;
}

__device__ __forceinline__ bf16x8 loadfrag_bf(const ushort_t* p) {
  u16x8v v = *(const u16x8v*)p;
  return __builtin_bit_cast(bf16x8, v);
}

__device__ __forceinline__ bf16x8 load8_cvt(const float* p) {
  f32x4 a = *(const f32x4*)p;
  f32x4 b = *(const f32x4*)(p + 4);
  u16x8v r;
  r[0] = bf16_rne(a[0]); r[1] = bf16_rne(a[1]);
  r[2] = bf16_rne(a[2]); r[3] = bf16_rne(a[3]);
  r[4] = bf16_rne(b[0]); r[5] = bf16_rne(b[1]);
  r[6] = bf16_rne(b[2]); r[7] = bf16_rne(b[3]);
  return __builtin_bit_cast(bf16x8, r);
}

__device__ __forceinline__ f32x4 mfma16(bf16x8 a, bf16x8 b, f32x4 c) {
  return __builtin_amdgcn_mfma_f32_16x16x32_bf16(a, b, c, 0, 0, 0);
}

__device__ __forceinline__ float readlane_f(float v, int lane) {
  return __builtin_bit_cast(float, __builtin_amdgcn_readlane(__builtin_bit_cast(int, v), lane));
}

__device__ __forceinline__ float fast_rcp(float x) {
  return __builtin_amdgcn_rcpf(x);
}

typedef const __attribute__((address_space(1))) void gv_t;
typedef __attribute__((address_space(3))) void lv_t;
__device__ __forceinline__ void gload_lds16(const void* g, void* l) {
  __builtin_amdgcn_global_load_lds((gv_t*)g, (lv_t*)l, 16, 0, 0);
}

// ---------------- weight fp32 -> bf16 ----------------
__global__ void cvt_weights(const float* __restrict__ wg,
                            const float* __restrict__ wu,
                            const float* __restrict__ wd,
                            ushort_t* __restrict__ o) {
  int i = blockIdx.x * 256 + threadIdx.x;
  const int n1 = DFFN * D;
  float v;
  if (i < n1)            v = wg[i];
  else if (i < 2 * n1)   v = wu[i - n1];
  else                   v = wd[i - 2 * n1];
  o[i] = bf16_rne(v);
}

// ---------------- Kernel A: geo + gate + LN -> pre-swizzled bf16 ----------------
__global__ __launch_bounds__(256)
void geo_ln(const float* __restrict__ x,
            const float* __restrict__ iw,
            const float* __restrict__ geo_gate,
            const float* __restrict__ ln_w,
            const float* __restrict__ ln_b,
            const float* __restrict__ cayley,
            ushort_t* __restrict__ Aout) {
  const int tid = threadIdx.x;
  const int w = tid >> 6;
  const int l = tid & 63;
  const int g = l >> 4;
  const int q = l & 15;

  float sgv;
  {
    int i_l = l >> 3, j_l = l & 7;
    float s = cayley[(i_l * 8 + j_l) * 8 + (i_l ^ j_l)];
    sgv = s / (1.0f + __expf(-iw[i_l * 8 + j_l]));
  }
  float cd[8], cp[28];
#pragma unroll
  for (int i = 0; i < 8; ++i) cd[i] = readlane_f(sgv, i * 8 + i);
  {
    int p = 0;
#pragma unroll
    for (int i = 0; i < 8; ++i)
#pragma unroll
      for (int j = i + 1; j < 8; ++j) { cp[p] = readlane_f(sgv, i * 8 + j) + readlane_f(sgv, j * 8 + i); ++p; }
  }
  const float gate = 1.0f / (1.0f + __expf(-geo_gate[0]));
  const float ogate = 1.0f - gate;

  const f32x4 lw0 = *(const f32x4*)(ln_w + q * 8);
  const f32x4 lw1 = *(const f32x4*)(ln_w + q * 8 + 4);
  const f32x4 lb0 = *(const f32x4*)(ln_b + q * 8);
  const f32x4 lb1 = *(const f32x4*)(ln_b + q * 8 + 4);

  const long tok = (long)blockIdx.x * 16 + w * 4 + g;
  const float* xp = x + tok * (NB * D) + q * 8;

  f32x4 xa[8], xb[8];
#pragma unroll
  for (int i = 0; i < 8; ++i) { xa[i] = *(const f32x4*)(xp + i * D); xb[i] = *(const f32x4*)(xp + i * D + 4); }

  f32x4 ga[8], gb[8];
#pragma unroll
  for (int k = 0; k < 8; ++k) { ga[k] = 0.f; gb[k] = 0.f; }
#pragma unroll
  for (int i = 0; i < 8; ++i) {
    ga[0] += cd[i] * (xa[i] * xa[i]);
    gb[0] += cd[i] * (xb[i] * xb[i]);
  }
  {
    int p = 0;
#pragma unroll
    for (int i = 0; i < 8; ++i)
#pragma unroll
      for (int j = i + 1; j < 8; ++j) {
        int k = i ^ j;
        ga[k] += cp[p] * (xa[i] * xa[j]);
        gb[k] += cp[p] * (xb[i] * xb[j]);
        ++p;
      }
  }

  ushort_t* Arow0 = Aout + tok * (8 * D);
#pragma unroll
  for (int k = 0; k < 8; ++k) {
    f32x4 m0 = gate * ga[k] + ogate * xa[k];
    f32x4 m1 = gate * gb[k] + ogate * xb[k];
    float s1 = (m0[0] + m0[1]) + (m0[2] + m0[3]) + (m1[0] + m1[1]) + (m1[2] + m1[3]);
    float s2 = m0[0]*m0[0] + m0[1]*m0[1] + m0[2]*m0[2] + m0[3]*m0[3]
             + m1[0]*m1[0] + m1[1]*m1[1] + m1[2]*m1[2] + m1[3]*m1[3];
#pragma unroll
    for (int off = 8; off; off >>= 1) {
      s1 += __shfl_xor(s1, off, 64);
      s2 += __shfl_xor(s2, off, 64);
    }
    float mu = s1 * (1.0f / 128.0f);
    float rs = rsqrtf(s2 * (1.0f / 128.0f) - mu * mu + LN_EPS);
    float nb2 = -mu * rs;
    f32x4 n0, n1;
#pragma unroll
    for (int e = 0; e < 4; ++e) {
      n0[e] = (m0[e] * rs + nb2) * lw0[e] + lb0[e];
      n1[e] = (m1[e] * rs + nb2) * lw1[e] + lb1[e];
    }
    uint32x4 pk;
    pk[0] = cvt_pk_bf16(n0[0], n0[1]);
    pk[1] = cvt_pk_bf16(n0[2], n0[3]);
    pk[2] = cvt_pk_bf16(n1[0], n1[1]);
    pk[3] = cvt_pk_bf16(n1[2], n1[3]);
    *(uint32x4*)(Arow0 + k * D + ((q ^ k) * 8)) = pk;
  }
}

// ---------------- Kernel B: SwiGLU FFN + residual (R11 body, 4 blocks/CU) ----------------
// BM=64, 4 waves. A staged to LDS then read ONCE into 16 pinned bf16x8 registers.
// GEMM1 register-fed; loop LDS traffic = H ping-pong only. One lgkm-only barrier
// per chunk. launch_bounds(256,4): 128-VGPR cap (body uses ~84), 4x32KB LDS.
__global__ __launch_bounds__(256, 4)
void ffn_mfma(const ushort_t* __restrict__ Abf,
              const float* __restrict__ x,
              const ushort_t* __restrict__ wg_bf,
              const ushort_t* __restrict__ wu_bf,
              const ushort_t* __restrict__ wd_bf,
              float* __restrict__ out) {
  __shared__ ushort_t A[64 * 128];        // 16KB swizzled (read once)
  __shared__ ushort_t Hb[2][64 * 64];     // 2 x 8KB ping-pong

  const int tid = threadIdx.x;
  const int w = tid >> 6;
  const int l = tid & 63;
  const int lg = l >> 4;
  const int ln16 = l & 15;

  const long row0 = (long)blockIdx.x * 64;

  // ---- stage A tile (pre-swizzled in global): 16 x 1KB segments ----
  {
    const ushort_t* src = Abf + row0 * D;
#pragma unroll
    for (int i = 0; i < 4; ++i) {
      int seg = w * 4 + i;
      gload_lds16(src + seg * 512 + l * 8, &A[seg * 512]);
    }
  }

  // ---- weights for chunk 0 (in flight with A staging) ----
  bf16x8 bg[4], bu[4], bd[2][2];
  {
    const int frow = w * 16 + ln16;
#pragma unroll
    for (int ks = 0; ks < 4; ++ks) {
      bg[ks] = loadfrag_bf(wg_bf + frow * D + ks * 32 + lg * 8);
      bu[ks] = loadfrag_bf(wu_bf + frow * D + ks * 32 + lg * 8);
    }
#pragma unroll
    for (int nt = 0; nt < 2; ++nt) {
      int dcol = w * 32 + nt * 16 + ln16;
#pragma unroll
      for (int k2 = 0; k2 < 2; ++k2)
        bd[nt][k2] = loadfrag_bf(wd_bf + dcol * DFFN + k2 * 32 + lg * 8);
    }
  }

  BARRIER_VM();   // A staged (global_load_lds requires vmcnt drain)

  // ---- A fragments -> registers ONCE; pin so they cannot be rematerialized ----
  bf16x8 afr[4][4];
#pragma unroll
  for (int mt = 0; mt < 4; ++mt) {
    const int row = mt * 16 + ln16;
#pragma unroll
    for (int ks = 0; ks < 4; ++ks) {
      int unit = (ks * 4 + lg) ^ (row & 7);
      afr[mt][ks] = *(const bf16x8*)&A[row * 128 + unit * 8];
    }
  }
#pragma unroll
  for (int mt = 0; mt < 4; ++mt)
#pragma unroll
    for (int ks = 0; ks < 4; ++ks)
      PIN(afr[mt][ks]);

  f32x4 oacc[4][2];
#pragma unroll
  for (int mt = 0; mt < 4; ++mt)
#pragma unroll
    for (int nt = 0; nt < 2; ++nt)
#pragma unroll
      for (int r = 0; r < 4; ++r) oacc[mt][nt][r] = 0.f;

#pragma unroll
  for (int ch = 0; ch < 8; ++ch) {
    ushort_t* Hc = &Hb[ch & 1][0];

    // ---- GEMM1 (register-fed, swapped) + silu + H write, per m-tile ----
#pragma unroll
    for (int mt = 0; mt < 4; ++mt) {
      const int row = mt * 16 + ln16;
      f32x4 gacc = 0.f, uacc = 0.f;
      __builtin_amdgcn_s_setprio(1);
#pragma unroll
      for (int ks = 0; ks < 4; ++ks) {
        gacc = mfma16(bg[ks], afr[mt][ks], gacc);
        uacc = mfma16(bu[ks], afr[mt][ks], uacc);
      }
      __builtin_amdgcn_s_setprio(0);
      float h[4];
#pragma unroll
      for (int r = 0; r < 4; ++r) {
        float gv = gacc[r];
        h[r] = gv * fast_rcp(1.0f + __expf(-gv)) * uacc[r];
      }
      uint32x2 pk;
      pk[0] = cvt_pk_bf16(h[0], h[1]);
      pk[1] = cvt_pk_bf16(h[2], h[3]);
      int u = (w * 2 + (lg >> 1)) ^ (row & 7);
      *(uint32x2*)((char*)Hc + row * 128 + u * 16 + (lg & 1) * 8) = pk;
    }

    // ---- prefetch next-chunk Wg/Wu (stays in flight across the barrier) ----
    if (ch < 7) {
      const int frow = (ch + 1) * 64 + w * 16 + ln16;
#pragma unroll
      for (int ks = 0; ks < 4; ++ks) {
        bg[ks] = loadfrag_bf(wg_bf + frow * D + ks * 32 + lg * 8);
        bu[ks] = loadfrag_bf(wu_bf + frow * D + ks * 32 + lg * 8);
      }
    }

    BARRIER_LGKM();   // H[ch&1] visible; vmcnt NOT drained

    // ---- GEMM2: O[m][d] += H @ Wd^T ; wave owns d = w*32..+32 ----
    __builtin_amdgcn_s_setprio(1);
#pragma unroll
    for (int mt = 0; mt < 4; ++mt) {
      const int m = mt * 16 + ln16;
#pragma unroll
      for (int k2 = 0; k2 < 2; ++k2) {
        int u = (k2 * 4 + lg) ^ (m & 7);
        bf16x8 hf = *(const bf16x8*)((const char*)Hc + m * 128 + u * 16);
        oacc[mt][0] = mfma16(hf, bd[0][k2], oacc[mt][0]);
        oacc[mt][1] = mfma16(hf, bd[1][k2], oacc[mt][1]);
      }
    }
    __builtin_amdgcn_s_setprio(0);

    // ---- prefetch next-chunk Wd (in flight until next GEMM2) ----
    if (ch < 7) {
#pragma unroll
      for (int nt = 0; nt < 2; ++nt) {
        int dcol = w * 32 + nt * 16 + ln16;
#pragma unroll
        for (int k2 = 0; k2 < 2; ++k2)
          bd[nt][k2] = loadfrag_bf(wd_bf + dcol * DFFN + (ch + 1) * 64 + k2 * 32 + lg * 8);
      }
    }
  }

  // ---- epilogue: out = x + O ----
#pragma unroll
  for (int mt = 0; mt < 4; ++mt) {
#pragma unroll
    for (int r = 0; r < 4; ++r) {
      long rowg = row0 + mt * 16 + lg * 4 + r;
      const float* xp = x + rowg * D;
      float* op = out + rowg * D;
#pragma unroll
      for (int nt = 0; nt < 2; ++nt) {
        int d = w * 32 + nt * 16 + ln16;
        op[d] = xp[d] + oacc[mt][nt][r];
      }
    }
  }
}

// ---------------- Fallback: fused kernel (used only if ws too small) ----------------
template <bool WS_BF16>
__global__ __launch_bounds__(256, 2)
void fused_geo_ffn(const float* __restrict__ x,
                   const float* __restrict__ iw,
                   const float* __restrict__ geo_gate,
                   const float* __restrict__ ln_w,
                   const float* __restrict__ ln_b,
                   const float* __restrict__ w_gate_f,
                   const float* __restrict__ w_up_f,
                   const float* __restrict__ w_down_f,
                   const float* __restrict__ cayley,
                   const ushort_t* __restrict__ wg_bf,
                   const ushort_t* __restrict__ wu_bf,
                   const ushort_t* __restrict__ wd_bf,
                   float* __restrict__ out) {
  __shared__ float sg[64];
  __shared__ ushort_t A_lds[128 * 128];
  __shared__ ushort_t H_lds[128 * 64];

  const int tid = threadIdx.x;
  const int w = tid >> 6;
  const int l = tid & 63;
  const int lg = l >> 4;
  const int ln16 = l & 15;
  const int kbase = lg * 8;

  if (tid < 64) {
    int i = tid >> 3, j = tid & 7;
    float s = cayley[(i * 8 + j) * 8 + (i ^ j)];
    sg[tid] = s / (1.0f + __expf(-iw[i * 8 + j]));
  }
  __syncthreads();
  float sgr[64];
#pragma unroll
  for (int t = 0; t < 64; ++t) sgr[t] = sg[t];

  const float gate = 1.0f / (1.0f + __expf(-geo_gate[0]));
  const float2 lw = *(const float2*)(ln_w + 2 * l);
  const float2 lb = *(const float2*)(ln_b + 2 * l);
  const long tok0 = (long)blockIdx.x * 16;

  for (int tt = 0; tt < 4; ++tt) {
    int ltok = w * 4 + tt;
    const float* xp = x + (tok0 + ltok) * (long)(NB * D);
    float2 xv[8];
#pragma unroll
    for (int i = 0; i < 8; ++i) xv[i] = *(const float2*)(xp + i * D + 2 * l);
#pragma unroll
    for (int k = 0; k < 8; ++k) {
      float2 g; g.x = 0.f; g.y = 0.f;
#pragma unroll
      for (int i = 0; i < 8; ++i) {
        float s = sgr[i * 8 + (i ^ k)];
        g.x += s * xv[i].x * xv[i ^ k].x;
        g.y += s * xv[i].y * xv[i ^ k].y;
      }
      float2 m;
      m.x = gate * g.x + (1.0f - gate) * xv[k].x;
      m.y = gate * g.y + (1.0f - gate) * xv[k].y;
      float s1 = m.x + m.y;
      float s2 = m.x * m.x + m.y * m.y;
#pragma unroll
      for (int off = 32; off; off >>= 1) {
        s1 += __shfl_xor(s1, off, 64);
        s2 += __shfl_xor(s2, off, 64);
      }
      float mu = s1 * (1.0f / 128.0f);
      float rs = rsqrtf(s2 * (1.0f / 128.0f) - mu * mu + LN_EPS);
      float nx = (m.x - mu) * rs * lw.x + lb.x;
      float ny = (m.y - mu) * rs * lw.y + lb.y;
      int row = ltok * 8 + k;
      int colb = (4 * l) ^ ((row & 7) << 4);
      *(unsigned*)((char*)A_lds + row * 256 + colb) = cvt_pk_bf16(nx, ny);
    }
  }
  __syncthreads();

  f32x4 oacc[8][2];
#pragma unroll
  for (int mt = 0; mt < 8; ++mt)
#pragma unroll
    for (int nt = 0; nt < 2; ++nt)
#pragma unroll
      for (int r = 0; r < 4; ++r) oacc[mt][nt][r] = 0.f;

  for (int ch = 0; ch < 8; ++ch) {
    const int fbase = ch * 64 + w * 16 + ln16;
    bf16x8 bg[4], bu[4];
#pragma unroll
    for (int ks = 0; ks < 4; ++ks) {
      int koff = ks * 32 + kbase;
      if (WS_BF16) {
        bg[ks] = loadfrag_bf(wg_bf + fbase * D + koff);
        bu[ks] = loadfrag_bf(wu_bf + fbase * D + koff);
      } else {
        bg[ks] = load8_cvt(w_gate_f + fbase * D + koff);
        bu[ks] = load8_cvt(w_up_f + fbase * D + koff);
      }
    }
#pragma unroll
    for (int mt = 0; mt < 8; ++mt) {
      const int row = mt * 16 + ln16;
      f32x4 gacc = 0.f, uacc = 0.f;
#pragma unroll
      for (int ks = 0; ks < 4; ++ks) {
        int colb = ((ks * 32 + kbase) * 2) ^ ((row & 7) << 4);
        bf16x8 a = *(const bf16x8*)((const char*)A_lds + row * 256 + colb);
        gacc = mfma16(bg[ks], a, gacc);
        uacc = mfma16(bu[ks], a, uacc);
      }
      float h[4];
#pragma unroll
      for (int r = 0; r < 4; ++r) {
        float gv = gacc[r], uv = uacc[r];
        h[r] = gv * __builtin_amdgcn_rcpf(1.0f + __expf(-gv)) * uv;
      }
      uint32x2 pk;
      pk[0] = cvt_pk_bf16(h[0], h[1]);
      pk[1] = cvt_pk_bf16(h[2], h[3]);
      int u = (w * 2 + (lg >> 1)) ^ (row & 7);
      *(uint32x2*)&H_lds[row * 64 + u * 8 + (lg & 1) * 4] = pk;
    }
    __syncthreads();
#pragma unroll
    for (int mt = 0; mt < 8; ++mt) {
      const int row = mt * 16 + ln16;
#pragma unroll
      for (int ks = 0; ks < 2; ++ks) {
        int u = (ks * 4 + lg) ^ (row & 7);
        bf16x8 hfrag = *(const bf16x8*)&H_lds[row * 64 + u * 8];
        bf16x8 b0, b1;
        int dcol0 = w * 32 + ln16;
        int foff = ch * 64 + ks * 32 + kbase;
        if (WS_BF16) {
          b0 = loadfrag_bf(wd_bf + dcol0 * DFFN + foff);
          b1 = loadfrag_bf(wd_bf + (dcol0 + 16) * DFFN + foff);
        } else {
          b0 = load8_cvt(w_down_f + dcol0 * DFFN + foff);
          b1 = load8_cvt(w_down_f + (dcol0 + 16) * DFFN + foff);
        }
        oacc[mt][0] = mfma16(hfrag, b0, oacc[mt][0]);
        oacc[mt][1] = mfma16(hfrag, b1, oacc[mt][1]);
      }
    }
    __syncthreads();
  }

  const long rowg0 = tok0 * NB;
#pragma unroll
  for (int mt = 0; mt < 8; ++mt) {
#pragma unroll
    for (int r = 0; r < 4; ++r) {
      long row = rowg0 + mt * 16 + lg * 4 + r;
      const float* xp = x + row * D;
      float* op = out + row * D;
#pragma unroll
      for (int nt = 0; nt < 2; ++nt) {
        int d = w * 32 + nt * 16 + ln16;
        op[d] = xp[d] + oacc[mt][nt][r];
      }
    }
  }
}

extern "C" void kernel_launch(void* const* d_in, const int* in_sizes, int n_in,
                              void* d_out, int out_size, void* d_ws, size_t ws_size,
                              hipStream_t stream) {
  const float* x   = (const float*)d_in[0];
  const float* iw  = (const float*)d_in[1];
  const float* gg  = (const float*)d_in[2];
  const float* lnw = (const float*)d_in[3];
  const float* lnb = (const float*)d_in[4];
  const float* wg  = (const float*)d_in[5];
  const float* wu  = (const float*)d_in[6];
  const float* wd  = (const float*)d_in[7];
  const float* cs  = (const float*)d_in[8];
  float* out = (float*)d_out;

  const int ntok = in_sizes[0] / (NB * D);          // 16384
  const int wtot = 3 * DFFN * D;                    // bf16 weight elems
  const size_t wbytes = (size_t)wtot * 2;           // 384KB
  const size_t abytes = (size_t)ntok * NB * D * 2;  // 33.5MB

  if (ws_size >= wbytes + abytes) {
    ushort_t* wbf = (ushort_t*)d_ws;
    ushort_t* act = wbf + wtot;
    cvt_weights<<<wtot / 256, 256, 0, stream>>>(wg, wu, wd, wbf);
    geo_ln<<<ntok / 16, 256, 0, stream>>>(x, iw, gg, lnw, lnb, cs, act);
    ffn_mfma<<<(ntok * NB) / 64, 256, 0, stream>>>(
        act, x, wbf, wbf + DFFN * D, wbf + 2 * DFFN * D, out);
  } else if (ws_size >= wbytes) {
    ushort_t* wbf = (ushort_t*)d_ws;
    cvt_weights<<<wtot / 256, 256, 0, stream>>>(wg, wu, wd, wbf);
    fused_geo_ffn<true><<<ntok / 16, 256, 0, stream>>>(
        x, iw, gg, lnw, lnb, wg, wu, wd, cs,
        wbf, wbf + DFFN * D, wbf + 2 * DFFN * D, out);
  } else {
    fused_geo_ffn<false><<<ntok / 16, 256, 0, stream>>>(
        x, iw, gg, lnw, lnb, wg, wu, wd, cs,
        (const ushort_t*)nullptr, (const ushort_t*)nullptr, (const ushort_t*)nullptr, out);
  }
}

// Round 13
// 113.675 us; speedup vs baseline: 2.1214x; 2.1214x over previous
//
#include <hip/hip_runtime.h>
#include <hip/hip_bf16.h>

typedef unsigned short ushort_t;
typedef __bf16 bf16_t;
typedef bf16_t bf16x8 __attribute__((ext_vector_type(8)));
typedef unsigned short u16x8v __attribute__((ext_vector_type(8)));
typedef float f32x4 __attribute__((ext_vector_type(4)));
typedef unsigned uint32x2 __attribute__((ext_vector_type(2)));
typedef unsigned uint32x4 __attribute__((ext_vector_type(4)));

#define D 128
#define NB 8
#define DFFN 512
#define LN_EPS 1e-5f

#define BARRIER_LGKM() asm volatile("s_waitcnt lgkmcnt(0)\n\ts_barrier" ::: "memory")
#define PIN(v) asm volatile("" : "+v"(v))

__device__ __forceinline__ ushort_t bf16_rne(float f) {
  union { float f; unsigned u; } c; c.f = f;
  unsigned u = c.u;
  unsigned r = (u + 0x7FFFu + ((u >> 16) & 1u)) >> 16;
  return (ushort_t)r;
}

__device__ __forceinline__ unsigned cvt_pk_bf16(float lo, float hi) {
  unsigned r;
  asm("v_cvt_pk_bf16_f32 %0, %1, %2" : "=v"(r) : "v"(lo), "v"(hi));
  return r;
}

__device__ __forceinline__ bf16x8 loadfrag_bf(const ushort_t* p) {
  u16x8v v = *(const u16x8v*)p;
  return __builtin_bit_cast(bf16x8, v);
}

__device__ __forceinline__ bf16x8 load8_cvt(const float* p) {
  f32x4 a = *(const f32x4*)p;
  f32x4 b = *(const f32x4*)(p + 4);
  u16x8v r;
  r[0] = bf16_rne(a[0]); r[1] = bf16_rne(a[1]);
  r[2] = bf16_rne(a[2]); r[3] = bf16_rne(a[3]);
  r[4] = bf16_rne(b[0]); r[5] = bf16_rne(b[1]);
  r[6] = bf16_rne(b[2]); r[7] = bf16_rne(b[3]);
  return __builtin_bit_cast(bf16x8, r);
}

__device__ __forceinline__ f32x4 mfma16(bf16x8 a, bf16x8 b, f32x4 c) {
  return __builtin_amdgcn_mfma_f32_16x16x32_bf16(a, b, c, 0, 0, 0);
}

__device__ __forceinline__ float readlane_f(float v, int lane) {
  return __builtin_bit_cast(float, __builtin_amdgcn_readlane(__builtin_bit_cast(int, v), lane));
}

__device__ __forceinline__ float fast_rcp(float x) {
  return __builtin_amdgcn_rcpf(x);
}

// ---------------- weight fp32 -> bf16 ----------------
__global__ void cvt_weights(const float* __restrict__ wg,
                            const float* __restrict__ wu,
                            const float* __restrict__ wd,
                            ushort_t* __restrict__ o) {
  int i = blockIdx.x * 256 + threadIdx.x;
  const int n1 = DFFN * D;
  float v;
  if (i < n1)            v = wg[i];
  else if (i < 2 * n1)   v = wu[i - n1];
  else                   v = wd[i - 2 * n1];
  o[i] = bf16_rne(v);
}

// ---------------- Fused: geo + gate + LN + SwiGLU FFN + residual ----------------
// BM=64 rows = 8 tokens, 4 waves. Phase 0: wave w computes tokens 2w,2w+1
// (geo/gate/LN, R1-verified full-wave layout) -> A_lds pre-swizzled bf16.
// Then R11 loop: A fragments pinned in registers, H ping-pong, one lgkm-only
// barrier per chunk, weight prefetch in flight across barriers.
__global__ __launch_bounds__(256, 3)
void geo_ffn_fused(const float* __restrict__ x,
                   const float* __restrict__ iw,
                   const float* __restrict__ geo_gate,
                   const float* __restrict__ ln_w,
                   const float* __restrict__ ln_b,
                   const float* __restrict__ cayley,
                   const ushort_t* __restrict__ wg_bf,
                   const ushort_t* __restrict__ wu_bf,
                   const ushort_t* __restrict__ wd_bf,
                   float* __restrict__ out) {
  __shared__ ushort_t A[64 * 128];        // 16KB swizzled
  __shared__ ushort_t Hb[2][64 * 64];     // 2 x 8KB ping-pong

  const int tid = threadIdx.x;
  const int w = tid >> 6;
  const int l = tid & 63;
  const int lg = l >> 4;
  const int ln16 = l & 15;

  const long tok0 = (long)blockIdx.x * 8;     // 8 tokens per block
  const long row0 = tok0 * NB;                // 64 rows

  // ---- weights for chunk 0 issued FIRST (latency hides under geo) ----
  bf16x8 bg[4], bu[4], bd[2][2];
  {
    const int frow = w * 16 + ln16;
#pragma unroll
    for (int ks = 0; ks < 4; ++ks) {
      bg[ks] = loadfrag_bf(wg_bf + frow * D + ks * 32 + lg * 8);
      bu[ks] = loadfrag_bf(wu_bf + frow * D + ks * 32 + lg * 8);
    }
#pragma unroll
    for (int nt = 0; nt < 2; ++nt) {
      int dcol = w * 32 + nt * 16 + ln16;
#pragma unroll
      for (int k2 = 0; k2 < 2; ++k2)
        bd[nt][k2] = loadfrag_bf(wd_bf + dcol * DFFN + k2 * 32 + lg * 8);
    }
  }

  // ---- Cayley*sigmoid coefficients (wave-uniform via readlane -> SGPRs) ----
  float cd[8], cp[28];
  {
    float sgv;
    int i_l = l >> 3, j_l = l & 7;
    float s = cayley[(i_l * 8 + j_l) * 8 + (i_l ^ j_l)];
    sgv = s / (1.0f + __expf(-iw[i_l * 8 + j_l]));
#pragma unroll
    for (int i = 0; i < 8; ++i) cd[i] = readlane_f(sgv, i * 8 + i);
    int p = 0;
#pragma unroll
    for (int i = 0; i < 8; ++i)
#pragma unroll
      for (int j = i + 1; j < 8; ++j) { cp[p] = readlane_f(sgv, i * 8 + j) + readlane_f(sgv, j * 8 + i); ++p; }
  }
  const float gate = 1.0f / (1.0f + __expf(-geo_gate[0]));
  const float ogate = 1.0f - gate;
  const float2 lw = *(const float2*)(ln_w + 2 * l);
  const float2 lb = *(const float2*)(ln_b + 2 * l);

  // ---- Phase 0: geo + gate + LN for wave's 2 tokens -> A_lds (pre-swizzled) ----
  for (int tt = 0; tt < 2; ++tt) {
    const int ltok = w * 2 + tt;
    const float* xp = x + (tok0 + ltok) * (long)(NB * D);
    float2 xv[8];
#pragma unroll
    for (int i = 0; i < 8; ++i) xv[i] = *(const float2*)(xp + i * D + 2 * l);
    float2 geo[8];
#pragma unroll
    for (int k = 0; k < 8; ++k) { geo[k].x = 0.f; geo[k].y = 0.f; }
#pragma unroll
    for (int i = 0; i < 8; ++i) {
      geo[0].x += cd[i] * xv[i].x * xv[i].x;
      geo[0].y += cd[i] * xv[i].y * xv[i].y;
    }
    {
      int p = 0;
#pragma unroll
      for (int i = 0; i < 8; ++i)
#pragma unroll
        for (int j = i + 1; j < 8; ++j) {
          int k = i ^ j;
          geo[k].x += cp[p] * (xv[i].x * xv[j].x);
          geo[k].y += cp[p] * (xv[i].y * xv[j].y);
          ++p;
        }
    }
#pragma unroll
    for (int k = 0; k < 8; ++k) {
      float mx = gate * geo[k].x + ogate * xv[k].x;
      float my = gate * geo[k].y + ogate * xv[k].y;
      float s1 = mx + my;
      float s2 = mx * mx + my * my;
#pragma unroll
      for (int off = 32; off; off >>= 1) {
        s1 += __shfl_xor(s1, off, 64);
        s2 += __shfl_xor(s2, off, 64);
      }
      float mu = s1 * (1.0f / 128.0f);
      float rs = rsqrtf(s2 * (1.0f / 128.0f) - mu * mu + LN_EPS);
      float nx = (mx - mu) * rs * lw.x + lb.x;
      float ny = (my - mu) * rs * lw.y + lb.y;
      int row = ltok * 8 + k;
      int colb = (4 * l) ^ ((row & 7) << 4);   // R1-verified write swizzle
      *(unsigned*)((char*)A + row * 256 + colb) = cvt_pk_bf16(nx, ny);
    }
  }

  BARRIER_LGKM();   // A_lds complete across waves

  // ---- A fragments -> registers ONCE; pin against rematerialization ----
  bf16x8 afr[4][4];
#pragma unroll
  for (int mt = 0; mt < 4; ++mt) {
    const int row = mt * 16 + ln16;
#pragma unroll
    for (int ks = 0; ks < 4; ++ks) {
      int unit = (ks * 4 + lg) ^ (row & 7);
      afr[mt][ks] = *(const bf16x8*)&A[row * 128 + unit * 8];
    }
  }
#pragma unroll
  for (int mt = 0; mt < 4; ++mt)
#pragma unroll
    for (int ks = 0; ks < 4; ++ks)
      PIN(afr[mt][ks]);

  f32x4 oacc[4][2];
#pragma unroll
  for (int mt = 0; mt < 4; ++mt)
#pragma unroll
    for (int nt = 0; nt < 2; ++nt)
#pragma unroll
      for (int r = 0; r < 4; ++r) oacc[mt][nt][r] = 0.f;

#pragma unroll
  for (int ch = 0; ch < 8; ++ch) {
    ushort_t* Hc = &Hb[ch & 1][0];

    // ---- GEMM1 (register-fed, swapped) + silu + H write ----
#pragma unroll
    for (int mt = 0; mt < 4; ++mt) {
      const int row = mt * 16 + ln16;
      f32x4 gacc = 0.f, uacc = 0.f;
      __builtin_amdgcn_s_setprio(1);
#pragma unroll
      for (int ks = 0; ks < 4; ++ks) {
        gacc = mfma16(bg[ks], afr[mt][ks], gacc);
        uacc = mfma16(bu[ks], afr[mt][ks], uacc);
      }
      __builtin_amdgcn_s_setprio(0);
      float h[4];
#pragma unroll
      for (int r = 0; r < 4; ++r) {
        float gv = gacc[r];
        h[r] = gv * fast_rcp(1.0f + __expf(-gv)) * uacc[r];
      }
      uint32x2 pk;
      pk[0] = cvt_pk_bf16(h[0], h[1]);
      pk[1] = cvt_pk_bf16(h[2], h[3]);
      int u = (w * 2 + (lg >> 1)) ^ (row & 7);
      *(uint32x2*)((char*)Hc + row * 128 + u * 16 + (lg & 1) * 8) = pk;
    }

    // ---- prefetch next-chunk Wg/Wu (in flight across the barrier) ----
    if (ch < 7) {
      const int frow = (ch + 1) * 64 + w * 16 + ln16;
#pragma unroll
      for (int ks = 0; ks < 4; ++ks) {
        bg[ks] = loadfrag_bf(wg_bf + frow * D + ks * 32 + lg * 8);
        bu[ks] = loadfrag_bf(wu_bf + frow * D + ks * 32 + lg * 8);
      }
    }

    BARRIER_LGKM();   // H[ch&1] visible; vmcnt NOT drained

    // ---- GEMM2: O[m][d] += H @ Wd^T ----
    __builtin_amdgcn_s_setprio(1);
#pragma unroll
    for (int mt = 0; mt < 4; ++mt) {
      const int m = mt * 16 + ln16;
#pragma unroll
      for (int k2 = 0; k2 < 2; ++k2) {
        int u = (k2 * 4 + lg) ^ (m & 7);
        bf16x8 hf = *(const bf16x8*)((const char*)Hc + m * 128 + u * 16);
        oacc[mt][0] = mfma16(hf, bd[0][k2], oacc[mt][0]);
        oacc[mt][1] = mfma16(hf, bd[1][k2], oacc[mt][1]);
      }
    }
    __builtin_amdgcn_s_setprio(0);

    // ---- prefetch next-chunk Wd ----
    if (ch < 7) {
#pragma unroll
      for (int nt = 0; nt < 2; ++nt) {
        int dcol = w * 32 + nt * 16 + ln16;
#pragma unroll
        for (int k2 = 0; k2 < 2; ++k2)
          bd[nt][k2] = loadfrag_bf(wd_bf + dcol * DFFN + (ch + 1) * 64 + k2 * 32 + lg * 8);
      }
    }
  }

  // ---- epilogue: out = x + O ----
#pragma unroll
  for (int mt = 0; mt < 4; ++mt) {
#pragma unroll
    for (int r = 0; r < 4; ++r) {
      long rowg = row0 + mt * 16 + lg * 4 + r;
      const float* xp = x + rowg * D;
      float* op = out + rowg * D;
#pragma unroll
      for (int nt = 0; nt < 2; ++nt) {
        int d = w * 32 + nt * 16 + ln16;
        op[d] = xp[d] + oacc[mt][nt][r];
      }
    }
  }
}

// ---------------- Fallback: fp32-weight fused kernel (ws too small) ----------------
__global__ __launch_bounds__(256, 2)
void fused_geo_ffn_f32w(const float* __restrict__ x,
                        const float* __restrict__ iw,
                        const float* __restrict__ geo_gate,
                        const float* __restrict__ ln_w,
                        const float* __restrict__ ln_b,
                        const float* __restrict__ w_gate_f,
                        const float* __restrict__ w_up_f,
                        const float* __restrict__ w_down_f,
                        const float* __restrict__ cayley,
                        float* __restrict__ out) {
  __shared__ float sg[64];
  __shared__ ushort_t A_lds[128 * 128];
  __shared__ ushort_t H_lds[128 * 64];

  const int tid = threadIdx.x;
  const int w = tid >> 6;
  const int l = tid & 63;
  const int lg = l >> 4;
  const int ln16 = l & 15;
  const int kbase = lg * 8;

  if (tid < 64) {
    int i = tid >> 3, j = tid & 7;
    float s = cayley[(i * 8 + j) * 8 + (i ^ j)];
    sg[tid] = s / (1.0f + __expf(-iw[i * 8 + j]));
  }
  __syncthreads();
  float sgr[64];
#pragma unroll
  for (int t = 0; t < 64; ++t) sgr[t] = sg[t];

  const float gate = 1.0f / (1.0f + __expf(-geo_gate[0]));
  const float2 lw = *(const float2*)(ln_w + 2 * l);
  const float2 lb = *(const float2*)(ln_b + 2 * l);
  const long tok0 = (long)blockIdx.x * 16;

  for (int tt = 0; tt < 4; ++tt) {
    int ltok = w * 4 + tt;
    const float* xp = x + (tok0 + ltok) * (long)(NB * D);
    float2 xv[8];
#pragma unroll
    for (int i = 0; i < 8; ++i) xv[i] = *(const float2*)(xp + i * D + 2 * l);
#pragma unroll
    for (int k = 0; k < 8; ++k) {
      float2 g; g.x = 0.f; g.y = 0.f;
#pragma unroll
      for (int i = 0; i < 8; ++i) {
        float s = sgr[i * 8 + (i ^ k)];
        g.x += s * xv[i].x * xv[i ^ k].x;
        g.y += s * xv[i].y * xv[i ^ k].y;
      }
      float2 m;
      m.x = gate * g.x + (1.0f - gate) * xv[k].x;
      m.y = gate * g.y + (1.0f - gate) * xv[k].y;
      float s1 = m.x + m.y;
      float s2 = m.x * m.x + m.y * m.y;
#pragma unroll
      for (int off = 32; off; off >>= 1) {
        s1 += __shfl_xor(s1, off, 64);
        s2 += __shfl_xor(s2, off, 64);
      }
      float mu = s1 * (1.0f / 128.0f);
      float rs = rsqrtf(s2 * (1.0f / 128.0f) - mu * mu + LN_EPS);
      float nx = (m.x - mu) * rs * lw.x + lb.x;
      float ny = (m.y - mu) * rs * lw.y + lb.y;
      int row = ltok * 8 + k;
      int colb = (4 * l) ^ ((row & 7) << 4);
      *(unsigned*)((char*)A_lds + row * 256 + colb) = cvt_pk_bf16(nx, ny);
    }
  }
  __syncthreads();

  f32x4 oacc[8][2];
#pragma unroll
  for (int mt = 0; mt < 8; ++mt)
#pragma unroll
    for (int nt = 0; nt < 2; ++nt)
#pragma unroll
      for (int r = 0; r < 4; ++r) oacc[mt][nt][r] = 0.f;

  for (int ch = 0; ch < 8; ++ch) {
    const int fbase = ch * 64 + w * 16 + ln16;
    bf16x8 bg[4], bu[4];
#pragma unroll
    for (int ks = 0; ks < 4; ++ks) {
      int koff = ks * 32 + kbase;
      bg[ks] = load8_cvt(w_gate_f + fbase * D + koff);
      bu[ks] = load8_cvt(w_up_f + fbase * D + koff);
    }
#pragma unroll
    for (int mt = 0; mt < 8; ++mt) {
      const int row = mt * 16 + ln16;
      f32x4 gacc = 0.f, uacc = 0.f;
#pragma unroll
      for (int ks = 0; ks < 4; ++ks) {
        int colb = ((ks * 32 + kbase) * 2) ^ ((row & 7) << 4);
        bf16x8 a = *(const bf16x8*)((const char*)A_lds + row * 256 + colb);
        gacc = mfma16(bg[ks], a, gacc);
        uacc = mfma16(bu[ks], a, uacc);
      }
      float h[4];
#pragma unroll
      for (int r = 0; r < 4; ++r) {
        float gv = gacc[r], uv = uacc[r];
        h[r] = gv * __builtin_amdgcn_rcpf(1.0f + __expf(-gv)) * uv;
      }
      uint32x2 pk;
      pk[0] = cvt_pk_bf16(h[0], h[1]);
      pk[1] = cvt_pk_bf16(h[2], h[3]);
      int u = (w * 2 + (lg >> 1)) ^ (row & 7);
      *(uint32x2*)&H_lds[row * 64 + u * 8 + (lg & 1) * 4] = pk;
    }
    __syncthreads();
#pragma unroll
    for (int mt = 0; mt < 8; ++mt) {
      const int row = mt * 16 + ln16;
#pragma unroll
      for (int ks = 0; ks < 2; ++ks) {
        int u = (ks * 4 + lg) ^ (row & 7);
        bf16x8 hfrag = *(const bf16x8*)&H_lds[row * 64 + u * 8];
        int dcol0 = w * 32 + ln16;
        int foff = ch * 64 + ks * 32 + kbase;
        bf16x8 b0 = load8_cvt(w_down_f + dcol0 * DFFN + foff);
        bf16x8 b1 = load8_cvt(w_down_f + (dcol0 + 16) * DFFN + foff);
        oacc[mt][0] = mfma16(hfrag, b0, oacc[mt][0]);
        oacc[mt][1] = mfma16(hfrag, b1, oacc[mt][1]);
      }
    }
    __syncthreads();
  }

  const long rowg0 = tok0 * NB;
#pragma unroll
  for (int mt = 0; mt < 8; ++mt) {
#pragma unroll
    for (int r = 0; r < 4; ++r) {
      long row = rowg0 + mt * 16 + lg * 4 + r;
      const float* xp = x + row * D;
      float* op = out + row * D;
#pragma unroll
      for (int nt = 0; nt < 2; ++nt) {
        int d = w * 32 + nt * 16 + ln16;
        op[d] = xp[d] + oacc[mt][nt][r];
      }
    }
  }
}

extern "C" void kernel_launch(void* const* d_in, const int* in_sizes, int n_in,
                              void* d_out, int out_size, void* d_ws, size_t ws_size,
                              hipStream_t stream) {
  const float* x   = (const float*)d_in[0];
  const float* iw  = (const float*)d_in[1];
  const float* gg  = (const float*)d_in[2];
  const float* lnw = (const float*)d_in[3];
  const float* lnb = (const float*)d_in[4];
  const float* wg  = (const float*)d_in[5];
  const float* wu  = (const float*)d_in[6];
  const float* wd  = (const float*)d_in[7];
  const float* cs  = (const float*)d_in[8];
  float* out = (float*)d_out;

  const int ntok = in_sizes[0] / (NB * D);          // 16384
  const int wtot = 3 * DFFN * D;                    // bf16 weight elems
  const size_t wbytes = (size_t)wtot * 2;           // 384KB

  if (ws_size >= wbytes) {
    ushort_t* wbf = (ushort_t*)d_ws;
    cvt_weights<<<wtot / 256, 256, 0, stream>>>(wg, wu, wd, wbf);
    geo_ffn_fused<<<ntok / 8, 256, 0, stream>>>(
        x, iw, gg, lnw, lnb, cs,
        wbf, wbf + DFFN * D, wbf + 2 * DFFN * D, out);
  } else {
    fused_geo_ffn_f32w<<<ntok / 16, 256, 0, stream>>>(
        x, iw, gg, lnw, lnb, wg, wu, wd, cs, out);
  }
}